// Round 6
// baseline (468.009 us; speedup 1.0000x reference)
//
#include <hip/hip_runtime.h>
#include <hip/hip_bf16.h>
#include <stdint.h>

// Problem constants
#define BB    4
#define NH    16
#define SEQ   2048
#define DH    64
#define EMB   1024
#define KD    1024
#define MROWS 8192   // BB*SEQ

typedef short  short8  __attribute__((ext_vector_type(8)));
typedef float  f32x4   __attribute__((ext_vector_type(4)));
typedef float  f32x16  __attribute__((ext_vector_type(16)));

typedef const __attribute__((address_space(1))) void* gas_t;
typedef __attribute__((address_space(3))) void*       las_t;
#define GLD16(g, l) __builtin_amdgcn_global_load_lds((gas_t)(g), (las_t)(l), 16, 0, 0)

__device__ __forceinline__ unsigned short f2bf(float f) {
    unsigned u = __float_as_uint(f);
    u += 0x7fffu + ((u >> 16) & 1u);   // RNE
    return (unsigned short)(u >> 16);
}
__device__ __forceinline__ unsigned packbf(float lo, float hi) {
    union { __hip_bfloat162 h; unsigned u; } cv;
    cv.h = __float22bfloat162_rn(make_float2(lo, hi));   // v_cvt_pk_bf16_f32
    return cv.u;
}

// ---------------------------------------------------------------------------
// Kernel 0: q/k/v fp32 -> bf16, merged (z picks tensor)
// ---------------------------------------------------------------------------
__global__ __launch_bounds__(256) void conv3_kernel(const float* __restrict__ qf,
                                                    const float* __restrict__ kf,
                                                    const float* __restrict__ vf,
                                                    unsigned short* __restrict__ dst) {
    const int p = blockIdx.z;
    const float* src = (p == 0) ? qf : (p == 1) ? kf : vf;
    unsigned short* d = dst + (size_t)p * ((size_t)MROWS * KD);
    const size_t i = ((size_t)blockIdx.x * 256 + threadIdx.x) * 8;
    float4 f0 = *(const float4*)(src + i);
    float4 f1 = *(const float4*)(src + i + 4);
    uint4 u;
    u.x = packbf(f0.x, f0.y); u.y = packbf(f0.z, f0.w);
    u.z = packbf(f1.x, f1.y); u.w = packbf(f1.z, f1.w);
    *(uint4*)(d + i) = u;
}

// ---------------------------------------------------------------------------
// Kernel 1: Wt[p][n][k] = bf16(W[p][k][n])
// ---------------------------------------------------------------------------
__global__ __launch_bounds__(256) void wt_kernel(const float* __restrict__ Wq,
                                                 const float* __restrict__ Wk,
                                                 const float* __restrict__ Wv,
                                                 unsigned short* __restrict__ Wt) {
    __shared__ float tsh[64 * 68];
    const int p = blockIdx.z;
    const float* W = (p == 0) ? Wq : (p == 1) ? Wk : Wv;
    unsigned short* dst = Wt + (size_t)p * (KD * EMB);
    const int k0 = blockIdx.x * 64, n0 = blockIdx.y * 64;
    const int t = threadIdx.x;
    {
        const int r = t >> 2, c4 = (t & 3) * 16;
        const float* g = W + (size_t)(k0 + r) * EMB + n0 + c4;
        float* row = &tsh[r * 68 + c4];
        *(float4*)(row + 0)  = *(const float4*)(g + 0);
        *(float4*)(row + 4)  = *(const float4*)(g + 4);
        *(float4*)(row + 8)  = *(const float4*)(g + 8);
        *(float4*)(row + 12) = *(const float4*)(g + 12);
    }
    __syncthreads();
    {
        const int j = t >> 2, kp = (t & 3) * 16;
        unsigned ub[8];
#pragma unroll
        for (int ii = 0; ii < 8; ++ii)
            ub[ii] = packbf(tsh[(kp + 2 * ii) * 68 + j], tsh[(kp + 2 * ii + 1) * 68 + j]);
        unsigned short* o = dst + (size_t)(n0 + j) * KD + k0 + kp;
        *(uint4*)(o + 0) = uint4{ub[0], ub[1], ub[2], ub[3]};
        *(uint4*)(o + 8) = uint4{ub[4], ub[5], ub[6], ub[7]};
    }
}

// ---------------------------------------------------------------------------
// Kernel 2: projection GEMM (round-3 proven: 128x128 tile, BK=64, 4 waves,
// XOR-swizzled DMA-staged LDS, ~176 us for all three projections).
// p=0: Q (scale folded), p=1: K, p=2: V (ReLU + [B,H,D,S] output).
// ---------------------------------------------------------------------------
__global__ __launch_bounds__(256) void proj_kernel(
    const unsigned short* __restrict__ AbfBase, const unsigned short* __restrict__ WtBase,
    const float* __restrict__ bq, const float* __restrict__ bk, const float* __restrict__ bv,
    unsigned short* __restrict__ Qg, unsigned short* __restrict__ Kg,
    unsigned short* __restrict__ Vt)
{
    __shared__ __align__(16) unsigned short smem[17408]; // A+B tiles 16384 U Tsh[128][136]
    unsigned short* Ash = smem;          // [128][64] swizzled
    unsigned short* Bsh = smem + 8192;   // [128][64] swizzled

    const int p = blockIdx.z;
    const unsigned short* Abf = AbfBase + (size_t)p * ((size_t)MROWS * KD);
    const unsigned short* Wp  = WtBase  + (size_t)p * (KD * EMB);
    const float* bias = (p == 0) ? bq : (p == 1) ? bk : bv;
    unsigned short* dst = (p == 0) ? Qg : (p == 1) ? Kg : Vt;

    const int row0 = blockIdx.x * 128;
    const int col0 = blockIdx.y * 128;
    const int t = threadIdx.x, lane = t & 63, wv = t >> 6;
    const int ln15 = lane & 15, q4 = lane >> 4;
    const int wm = wv & 1, wn = wv >> 1;

    f32x4 acc[4][4];
#pragma unroll
    for (int i = 0; i < 4; ++i)
#pragma unroll
        for (int j = 0; j < 4; ++j)
#pragma unroll
            for (int r = 0; r < 4; ++r) acc[i][j][r] = 0.f;

    const int lr = lane >> 3, lc = (lane & 7) ^ lr;
    const unsigned short* gA = Abf + (size_t)(row0 + wv * 32 + lr) * KD + lc * 8;
    const unsigned short* gB = Wp  + (size_t)(col0 + wv * 32 + lr) * KD + lc * 8;
    unsigned short* lA = Ash + wv * 32 * 64;
    unsigned short* lB = Bsh + wv * 32 * 64;

    for (int k0 = 0; k0 < KD; k0 += 64) {
#pragma unroll
        for (int i = 0; i < 4; ++i) {
            GLD16(gA + (size_t)i * 8 * KD + k0, lA + i * 512);
            GLD16(gB + (size_t)i * 8 * KD + k0, lB + i * 512);
        }
        __syncthreads();
#pragma unroll
        for (int kk = 0; kk < 2; ++kk) {
            short8 af[4], bfr[4];
#pragma unroll
            for (int mi = 0; mi < 4; ++mi) {
                const int r = wm * 64 + mi * 16 + ln15;
                af[mi] = *(const short8*)&Ash[r * 64 + (((kk << 2) | q4) ^ (r & 7)) * 8];
            }
#pragma unroll
            for (int ni = 0; ni < 4; ++ni) {
                const int r = wn * 64 + ni * 16 + ln15;
                bfr[ni] = *(const short8*)&Bsh[r * 64 + (((kk << 2) | q4) ^ (r & 7)) * 8];
            }
#pragma unroll
            for (int mi = 0; mi < 4; ++mi)
#pragma unroll
                for (int ni = 0; ni < 4; ++ni)
                    acc[mi][ni] = __builtin_amdgcn_mfma_f32_16x16x32_bf16(
                        af[mi], bfr[ni], acc[mi][ni], 0, 0, 0);
        }
        __syncthreads();
    }

    float bvv[4];
#pragma unroll
    for (int ni = 0; ni < 4; ++ni) bvv[ni] = bias[col0 + wn * 64 + ni * 16 + ln15];
    const float scq = 0.18033688011112042f;   // log2(e)/sqrt(64), folded into Q

    unsigned short* Tsh = smem;   // [128][136]
#pragma unroll
    for (int mi = 0; mi < 4; ++mi)
#pragma unroll
        for (int ni = 0; ni < 4; ++ni)
#pragma unroll
            for (int r = 0; r < 4; ++r) {
                const int mr = wm * 64 + mi * 16 + q4 * 4 + r;
                const int ec = wn * 64 + ni * 16 + ln15;
                float vv = acc[mi][ni][r] + bvv[ni];
                if (p == 0) vv *= scq;
                if (p == 2) vv = vv > 0.f ? vv : 0.f;   // ReLU
                Tsh[mr * 136 + ec] = f2bf(vv);
            }
    __syncthreads();

    if (p < 2) {
        const int mr = t >> 1, hsel = t & 1;
        const int m = row0 + mr, bi = m >> 11, s = m & 2047;
        const int hh = (col0 >> 6) + hsel;
        const unsigned short* src = &Tsh[mr * 136 + hsel * 64];
        unsigned short* o = dst + ((size_t)(bi * NH + hh) * SEQ + s) * DH;
#pragma unroll
        for (int c = 0; c < 8; ++c)
            *(uint4*)(o + 8 * c) = *(const uint4*)(src + 8 * c);
    } else {
        const int e = t >> 1, sh2 = t & 1;
        const int n = col0 + e, hh = n >> 6, dd = n & 63;
        const int bi = row0 >> 11, sbase = (row0 & 2047) + sh2 * 64;
        unsigned ub[32];
#pragma unroll
        for (int i = 0; i < 32; ++i)
            ub[i] = (unsigned)Tsh[(sh2 * 64 + 2 * i) * 136 + e] |
                    ((unsigned)Tsh[(sh2 * 64 + 2 * i + 1) * 136 + e] << 16);
        unsigned short* o = dst + ((size_t)(bi * NH + hh) * DH + dd) * SEQ + sbase;
#pragma unroll
        for (int c = 0; c < 8; ++c)
            *(uint4*)(o + 8 * c) = uint4{ub[4 * c], ub[4 * c + 1], ub[4 * c + 2], ub[4 * c + 3]};
    }
}

// ---------------------------------------------------------------------------
// Kernel 3: flash attention, 32x32x16 bf16 mfma, S^T = K*Q^T formulation.
// BARRIER-FREE: no LDS in the main loop; every MFMA operand fragment is a
// 16B-contiguous global load (K rows in [B,H,S,D], V^T rows in [B,H,D,S]),
// L2-resident across the 16 q-blocks per (b,h).  No-max softmax (Q carries
// log2(e)/sqrt(64)), L via ones-MFMA, direct AGPR->global epilogue.
// ---------------------------------------------------------------------------
__global__ __launch_bounds__(256) void attn_kernel(
    const unsigned short* __restrict__ Qg, const unsigned short* __restrict__ Kg,
    const unsigned short* __restrict__ Vt, float* __restrict__ out)
{
    const int qb = blockIdx.x, hh = blockIdx.y, bb = blockIdx.z;
    const int t = threadIdx.x, lane = t & 63, wv = t >> 6;
    const int ln31 = lane & 31, h2 = lane >> 5;
    const size_t bh = (size_t)(bb * NH + hh);
    const unsigned short* Qp = Qg + bh * (SEQ * DH);
    // lane-resolved base pointers: row ln31, 16B chunk h2
    const unsigned short* Kp = Kg + bh * (SEQ * DH) + (size_t)ln31 * DH  + h2 * 8;
    const unsigned short* Vp = Vt + bh * (DH * SEQ) + (size_t)ln31 * SEQ + h2 * 8;
    const int q0 = qb * 128 + wv * 32;

    short8 qf[4];
#pragma unroll
    for (int dc = 0; dc < 4; ++dc)
        qf[dc] = *(const short8*)(Qp + (size_t)(q0 + ln31) * DH + h2 * 8 + dc * 16);

    short8 ones;
#pragma unroll
    for (int i = 0; i < 8; ++i) ones[i] = (short)0x3F80;   // bf16 1.0

    f32x16 accO[2], accL;
#pragma unroll
    for (int i = 0; i < 16; ++i) { accO[0][i] = 0.f; accO[1][i] = 0.f; accL[i] = 0.f; }

    for (int kt0 = 0; kt0 < SEQ; kt0 += 64) {
        // K fragments: A-operand rows kt0+kt*32+ln31, k-chunk h2*8+dc*16
        short8 kfr[2][4];
#pragma unroll
        for (int kt = 0; kt < 2; ++kt)
#pragma unroll
            for (int dc = 0; dc < 4; ++dc)
                kfr[kt][dc] = *(const short8*)(Kp + (size_t)(kt0 + kt * 32) * DH + dc * 16);

        // V^T fragments for this key tile (hoisted: shadowed by exp2 block)
        short8 vfr[2][4];   // [dt][nc]
#pragma unroll
        for (int dt = 0; dt < 2; ++dt)
#pragma unroll
            for (int nc = 0; nc < 4; ++nc)
                vfr[dt][nc] = *(const short8*)(Vp + (size_t)(dt * 32) * SEQ + kt0 + nc * 16);

        // S^T[key][q] = K·Q^T   (Q pre-scaled, exp2 domain)
        f32x16 st[2];
#pragma unroll
        for (int kt = 0; kt < 2; ++kt) {
#pragma unroll
            for (int i = 0; i < 16; ++i) st[kt][i] = 0.f;
#pragma unroll
            for (int dc = 0; dc < 4; ++dc)
                st[kt] = __builtin_amdgcn_mfma_f32_32x32x16_bf16(kfr[kt][dc], qf[dc], st[kt], 0, 0, 0);
        }
        // P = exp2(S)   (no max subtraction: |S| bounded, fp32-safe)
#pragma unroll
        for (int kt = 0; kt < 2; ++kt)
#pragma unroll
            for (int r = 0; r < 16; ++r)
                st[kt][r] = __builtin_amdgcn_exp2f(st[kt][r]);

        // P^T -> B-frags via cross-half shuffle; L += 1^T·P^T; O^T += V^T·P^T
#pragma unroll
        for (int kt = 0; kt < 2; ++kt) {
            unsigned ow[8], xw[8];
#pragma unroll
            for (int i = 0; i < 8; ++i) {
                ow[i] = packbf(st[kt][2 * i], st[kt][2 * i + 1]);
                xw[i] = (unsigned)__shfl_xor((int)ow[i], 32);
            }
#pragma unroll
            for (int kc = 0; kc < 2; ++kc) {
                union { unsigned u[4]; short8 v; } pf;
                pf.u[0] = h2 ? xw[4 * kc + 2] : ow[4 * kc + 0];
                pf.u[1] = h2 ? xw[4 * kc + 3] : ow[4 * kc + 1];
                pf.u[2] = h2 ? ow[4 * kc + 2] : xw[4 * kc + 0];
                pf.u[3] = h2 ? ow[4 * kc + 3] : xw[4 * kc + 1];
                const int nc = kt * 2 + kc;
                accL = __builtin_amdgcn_mfma_f32_32x32x16_bf16(ones, pf.v, accL, 0, 0, 0);
#pragma unroll
                for (int dt = 0; dt < 2; ++dt)
                    accO[dt] = __builtin_amdgcn_mfma_f32_32x32x16_bf16(vfr[dt][nc], pf.v, accO[dt], 0, 0, 0);
            }
        }
    }

    // epilogue: direct from AGPR C-layout.  lane q = q0+ln31; regs 4g+j of
    // accO[dt] are d = dt*32 + 4*h2 + 8*g + j  -> contiguous float4 chunks.
    const float inv = 1.0f / accL[0];
    float* orow = out + ((size_t)(bb * SEQ + q0 + ln31) * NH + hh) * 64;
#pragma unroll
    for (int dt = 0; dt < 2; ++dt)
#pragma unroll
        for (int g = 0; g < 4; ++g) {
            float4 w;
            w.x = accO[dt][4 * g + 0] * inv;
            w.y = accO[dt][4 * g + 1] * inv;
            w.z = accO[dt][4 * g + 2] * inv;
            w.w = accO[dt][4 * g + 3] * inv;
            *(float4*)(orow + dt * 32 + 4 * h2 + 8 * g) = w;
        }
}

// ---------------------------------------------------------------------------
extern "C" void kernel_launch(void* const* d_in, const int* in_sizes, int n_in,
                              void* d_out, int out_size, void* d_ws, size_t ws_size,
                              hipStream_t stream) {
    const float* qf = (const float*)d_in[0];
    const float* kf = (const float*)d_in[1];
    const float* vf = (const float*)d_in[2];
    const float* Wq = (const float*)d_in[3];
    const float* bq = (const float*)d_in[4];
    const float* Wk = (const float*)d_in[5];
    const float* bk = (const float*)d_in[6];
    const float* Wv = (const float*)d_in[7];
    const float* bv = (const float*)d_in[8];

    char* ws = (char*)d_ws;
    unsigned short* Wt  = (unsigned short*)ws;               // 6 MB
    unsigned short* Qg  = (unsigned short*)(ws + 6291456);   // 16 MB [B,H,S,D]
    unsigned short* Kg  = Qg + 8388608;                      // 16 MB [B,H,S,D]
    unsigned short* Vt  = Kg + 8388608;                      // 16 MB [B,H,D,S]
    unsigned short* Ab  = Vt + 8388608;                      // 3 x 16 MB bf16 A
    float* out = (float*)d_out;

    wt_kernel<<<dim3(16, 16, 3), 256, 0, stream>>>(Wq, Wk, Wv, Wt);
    conv3_kernel<<<dim3(4096, 1, 3), 256, 0, stream>>>(qf, kf, vf, Ab);
    proj_kernel<<<dim3(64, 8, 3), 256, 0, stream>>>(Ab, Wt, bq, bk, bv, Qg, Kg, Vt);
    attn_kernel<<<dim3(16, 16, 4), 256, 0, stream>>>(Qg, Kg, Vt, out);
}

// Round 7
// 314.784 us; speedup vs baseline: 1.4868x; 1.4868x over previous
//
#include <hip/hip_runtime.h>
#include <hip/hip_bf16.h>
#include <stdint.h>

// Problem constants
#define BB    4
#define NH    16
#define SEQ   2048
#define DH    64
#define EMB   1024
#define KD    1024
#define MROWS 8192   // BB*SEQ

typedef short  short8  __attribute__((ext_vector_type(8)));
typedef float  f32x4   __attribute__((ext_vector_type(4)));
typedef float  f32x16  __attribute__((ext_vector_type(16)));

typedef const __attribute__((address_space(1))) void* gas_t;
typedef __attribute__((address_space(3))) void*       las_t;
#define GLD16(g, l) __builtin_amdgcn_global_load_lds((gas_t)(g), (las_t)(l), 16, 0, 0)

__device__ __forceinline__ unsigned short f2bf(float f) {
    unsigned u = __float_as_uint(f);
    u += 0x7fffu + ((u >> 16) & 1u);   // RNE
    return (unsigned short)(u >> 16);
}
__device__ __forceinline__ unsigned packbf(float lo, float hi) {
    union { __hip_bfloat162 h; unsigned u; } cv;
    cv.h = __float22bfloat162_rn(make_float2(lo, hi));   // v_cvt_pk_bf16_f32
    return cv.u;
}

// ---------------------------------------------------------------------------
// Kernel 0: q/k/v fp32 -> bf16, merged (z picks tensor)
// ---------------------------------------------------------------------------
__global__ __launch_bounds__(256) void conv3_kernel(const float* __restrict__ qf,
                                                    const float* __restrict__ kf,
                                                    const float* __restrict__ vf,
                                                    unsigned short* __restrict__ dst) {
    const int p = blockIdx.z;
    const float* src = (p == 0) ? qf : (p == 1) ? kf : vf;
    unsigned short* d = dst + (size_t)p * ((size_t)MROWS * KD);
    const size_t i = ((size_t)blockIdx.x * 256 + threadIdx.x) * 8;
    float4 f0 = *(const float4*)(src + i);
    float4 f1 = *(const float4*)(src + i + 4);
    uint4 u;
    u.x = packbf(f0.x, f0.y); u.y = packbf(f0.z, f0.w);
    u.z = packbf(f1.x, f1.y); u.w = packbf(f1.z, f1.w);
    *(uint4*)(d + i) = u;
}

// ---------------------------------------------------------------------------
// Kernel 1: Wt[p][n][k] = bf16(W[p][k][n])
// ---------------------------------------------------------------------------
__global__ __launch_bounds__(256) void wt_kernel(const float* __restrict__ Wq,
                                                 const float* __restrict__ Wk,
                                                 const float* __restrict__ Wv,
                                                 unsigned short* __restrict__ Wt) {
    __shared__ float tsh[64 * 68];
    const int p = blockIdx.z;
    const float* W = (p == 0) ? Wq : (p == 1) ? Wk : Wv;
    unsigned short* dst = Wt + (size_t)p * (KD * EMB);
    const int k0 = blockIdx.x * 64, n0 = blockIdx.y * 64;
    const int t = threadIdx.x;
    {
        const int r = t >> 2, c4 = (t & 3) * 16;
        const float* g = W + (size_t)(k0 + r) * EMB + n0 + c4;
        float* row = &tsh[r * 68 + c4];
        *(float4*)(row + 0)  = *(const float4*)(g + 0);
        *(float4*)(row + 4)  = *(const float4*)(g + 4);
        *(float4*)(row + 8)  = *(const float4*)(g + 8);
        *(float4*)(row + 12) = *(const float4*)(g + 12);
    }
    __syncthreads();
    {
        const int j = t >> 2, kp = (t & 3) * 16;
        unsigned ub[8];
#pragma unroll
        for (int ii = 0; ii < 8; ++ii)
            ub[ii] = packbf(tsh[(kp + 2 * ii) * 68 + j], tsh[(kp + 2 * ii + 1) * 68 + j]);
        unsigned short* o = dst + (size_t)(n0 + j) * KD + k0 + kp;
        *(uint4*)(o + 0) = uint4{ub[0], ub[1], ub[2], ub[3]};
        *(uint4*)(o + 8) = uint4{ub[4], ub[5], ub[6], ub[7]};
    }
}

// ---------------------------------------------------------------------------
// Kernel 2: projection GEMM (round-3 proven: 128x128 tile, BK=64, 4 waves,
// XOR-swizzled DMA-staged LDS).
// p=0: Q (scale folded), p=1: K, p=2: V (ReLU + [B,H,D,S] output).
// ---------------------------------------------------------------------------
__global__ __launch_bounds__(256) void proj_kernel(
    const unsigned short* __restrict__ AbfBase, const unsigned short* __restrict__ WtBase,
    const float* __restrict__ bq, const float* __restrict__ bk, const float* __restrict__ bv,
    unsigned short* __restrict__ Qg, unsigned short* __restrict__ Kg,
    unsigned short* __restrict__ Vt)
{
    __shared__ __align__(16) unsigned short smem[17408]; // A+B tiles 16384 U Tsh[128][136]
    unsigned short* Ash = smem;          // [128][64] swizzled
    unsigned short* Bsh = smem + 8192;   // [128][64] swizzled

    const int p = blockIdx.z;
    const unsigned short* Abf = AbfBase + (size_t)p * ((size_t)MROWS * KD);
    const unsigned short* Wp  = WtBase  + (size_t)p * (KD * EMB);
    const float* bias = (p == 0) ? bq : (p == 1) ? bk : bv;
    unsigned short* dst = (p == 0) ? Qg : (p == 1) ? Kg : Vt;

    const int row0 = blockIdx.x * 128;
    const int col0 = blockIdx.y * 128;
    const int t = threadIdx.x, lane = t & 63, wv = t >> 6;
    const int ln15 = lane & 15, q4 = lane >> 4;
    const int wm = wv & 1, wn = wv >> 1;

    f32x4 acc[4][4];
#pragma unroll
    for (int i = 0; i < 4; ++i)
#pragma unroll
        for (int j = 0; j < 4; ++j)
#pragma unroll
            for (int r = 0; r < 4; ++r) acc[i][j][r] = 0.f;

    const int lr = lane >> 3, lc = (lane & 7) ^ lr;
    const unsigned short* gA = Abf + (size_t)(row0 + wv * 32 + lr) * KD + lc * 8;
    const unsigned short* gB = Wp  + (size_t)(col0 + wv * 32 + lr) * KD + lc * 8;
    unsigned short* lA = Ash + wv * 32 * 64;
    unsigned short* lB = Bsh + wv * 32 * 64;

    for (int k0 = 0; k0 < KD; k0 += 64) {
#pragma unroll
        for (int i = 0; i < 4; ++i) {
            GLD16(gA + (size_t)i * 8 * KD + k0, lA + i * 512);
            GLD16(gB + (size_t)i * 8 * KD + k0, lB + i * 512);
        }
        __syncthreads();
#pragma unroll
        for (int kk = 0; kk < 2; ++kk) {
            short8 af[4], bfr[4];
#pragma unroll
            for (int mi = 0; mi < 4; ++mi) {
                const int r = wm * 64 + mi * 16 + ln15;
                af[mi] = *(const short8*)&Ash[r * 64 + (((kk << 2) | q4) ^ (r & 7)) * 8];
            }
#pragma unroll
            for (int ni = 0; ni < 4; ++ni) {
                const int r = wn * 64 + ni * 16 + ln15;
                bfr[ni] = *(const short8*)&Bsh[r * 64 + (((kk << 2) | q4) ^ (r & 7)) * 8];
            }
#pragma unroll
            for (int mi = 0; mi < 4; ++mi)
#pragma unroll
                for (int ni = 0; ni < 4; ++ni)
                    acc[mi][ni] = __builtin_amdgcn_mfma_f32_16x16x32_bf16(
                        af[mi], bfr[ni], acc[mi][ni], 0, 0, 0);
        }
        __syncthreads();
    }

    float bvv[4];
#pragma unroll
    for (int ni = 0; ni < 4; ++ni) bvv[ni] = bias[col0 + wn * 64 + ni * 16 + ln15];
    const float scq = 0.18033688011112042f;   // log2(e)/sqrt(64), folded into Q

    unsigned short* Tsh = smem;   // [128][136]
#pragma unroll
    for (int mi = 0; mi < 4; ++mi)
#pragma unroll
        for (int ni = 0; ni < 4; ++ni)
#pragma unroll
            for (int r = 0; r < 4; ++r) {
                const int mr = wm * 64 + mi * 16 + q4 * 4 + r;
                const int ec = wn * 64 + ni * 16 + ln15;
                float vv = acc[mi][ni][r] + bvv[ni];
                if (p == 0) vv *= scq;
                if (p == 2) vv = vv > 0.f ? vv : 0.f;   // ReLU
                Tsh[mr * 136 + ec] = f2bf(vv);
            }
    __syncthreads();

    if (p < 2) {
        const int mr = t >> 1, hsel = t & 1;
        const int m = row0 + mr, bi = m >> 11, s = m & 2047;
        const int hh = (col0 >> 6) + hsel;
        const unsigned short* src = &Tsh[mr * 136 + hsel * 64];
        unsigned short* o = dst + ((size_t)(bi * NH + hh) * SEQ + s) * DH;
#pragma unroll
        for (int c = 0; c < 8; ++c)
            *(uint4*)(o + 8 * c) = *(const uint4*)(src + 8 * c);
    } else {
        const int e = t >> 1, sh2 = t & 1;
        const int n = col0 + e, hh = n >> 6, dd = n & 63;
        const int bi = row0 >> 11, sbase = (row0 & 2047) + sh2 * 64;
        unsigned ub[32];
#pragma unroll
        for (int i = 0; i < 32; ++i)
            ub[i] = (unsigned)Tsh[(sh2 * 64 + 2 * i) * 136 + e] |
                    ((unsigned)Tsh[(sh2 * 64 + 2 * i + 1) * 136 + e] << 16);
        unsigned short* o = dst + ((size_t)(bi * NH + hh) * DH + dd) * SEQ + sbase;
#pragma unroll
        for (int c = 0; c < 8; ++c)
            *(uint4*)(o + 8 * c) = uint4{ub[4 * c], ub[4 * c + 1], ub[4 * c + 2], ub[4 * c + 3]};
    }
}

// ---------------------------------------------------------------------------
// Kernel 3: flash attention, 32x32x16 bf16 mfma, S^T = K*Q^T formulation.
// KEY-PERMUTED K staging (rows 4-7<->8-11, 20-23<->24-27 per 32): the S^T
// C-layout registers then hold 8-consecutive-key runs per half, so PV
// B-fragments are direct packs of st regs -- NO cross-lane shuffles.
// Double-buffered K/V LDS tiles, ONE barrier per iter (loads for tile i+1
// issue before the barrier, ds_writes after compute).
// No-max softmax (Q pre-scaled by log2(e)/sqrt(64)), L via ones-MFMA,
// direct AGPR->global epilogue.
// ---------------------------------------------------------------------------
__global__ __launch_bounds__(256) void attn_kernel(
    const unsigned short* __restrict__ Qg, const unsigned short* __restrict__ Kg,
    const unsigned short* __restrict__ Vt, float* __restrict__ out)
{
    // buffer b: K at smem + b*9216, V at smem + b*9216 + 4608 (shorts, pitch 72)
    __shared__ __align__(16) unsigned short smem[18432];   // 36864 B

    const int qb = blockIdx.x, hh = blockIdx.y, bb = blockIdx.z;
    const int t = threadIdx.x, lane = t & 63, wv = t >> 6;
    const int ln31 = lane & 31, h2 = lane >> 5;
    const size_t bh = (size_t)(bb * NH + hh);
    const unsigned short* Qp = Qg + bh * (SEQ * DH);
    const unsigned short* Kp = Kg + bh * (SEQ * DH);
    const unsigned short* Vp = Vt + bh * (DH * SEQ);
    const int q0 = qb * 128 + wv * 32;

    short8 qf[4];
#pragma unroll
    for (int dc = 0; dc < 4; ++dc)
        qf[dc] = *(const short8*)(Qp + (size_t)(q0 + ln31) * DH + h2 * 8 + dc * 16);

    short8 ones;
#pragma unroll
    for (int i = 0; i < 8; ++i) ones[i] = (short)0x3F80;   // bf16 1.0

    f32x16 accO[2], accL;
#pragma unroll
    for (int i = 0; i < 16; ++i) { accO[0][i] = 0.f; accO[1][i] = 0.f; accL[i] = 0.f; }

    // staging: thread -> K row srow (store to permuted row), V^T row srow
    const int srow = t >> 2, sp = (t & 3) * 16;
    const int prow = srow ^ (((((srow >> 2) ^ (srow >> 3)) & 1)) ? 12 : 0);
    const unsigned short* gk = Kp + (size_t)srow * DH + sp;
    const unsigned short* gv = Vp + (size_t)srow * SEQ + sp;
    const int wkoff = prow * 72 + sp;           // K write offset within buffer
    const int wvoff = 4608 + srow * 72 + sp;    // V write offset within buffer

    {   // prologue: stage tile 0 into buffer 0
        short8 ka = *(const short8*)(gk), kb = *(const short8*)(gk + 8);
        short8 va = *(const short8*)(gv), vb = *(const short8*)(gv + 8);
        *(short8*)&smem[wkoff] = ka; *(short8*)&smem[wkoff + 8] = kb;
        *(short8*)&smem[wvoff] = va; *(short8*)&smem[wvoff + 8] = vb;
    }

    for (int it = 0; it < 32; ++it) {
        // issue next tile's global loads before the barrier (wraps at end)
        const int nxt = (it + 1) & 31;
        short8 ka = *(const short8*)(gk + (size_t)nxt * 64 * DH);
        short8 kb = *(const short8*)(gk + (size_t)nxt * 64 * DH + 8);
        short8 va = *(const short8*)(gv + nxt * 64);
        short8 vb = *(const short8*)(gv + nxt * 64 + 8);

        __syncthreads();   // buffer (it&1) fully staged by all waves

        const unsigned short* Ksh = smem + (it & 1) * 9216;
        const unsigned short* Vsh = Ksh + 4608;

        // S^T[key][q] = K·Q^T  (rows permuted via staging; Q pre-scaled)
        f32x16 st[2];
#pragma unroll
        for (int kt = 0; kt < 2; ++kt) {
#pragma unroll
            for (int i = 0; i < 16; ++i) st[kt][i] = 0.f;
#pragma unroll
            for (int dc = 0; dc < 4; ++dc) {
                short8 kf = *(const short8*)&Ksh[(kt * 32 + ln31) * 72 + h2 * 8 + dc * 16];
                st[kt] = __builtin_amdgcn_mfma_f32_32x32x16_bf16(kf, qf[dc], st[kt], 0, 0, 0);
            }
        }
        // P = exp2(S)  (no max subtraction: |S| bounded, fp32-safe)
#pragma unroll
        for (int kt = 0; kt < 2; ++kt)
#pragma unroll
            for (int r = 0; r < 16; ++r)
                st[kt][r] = __builtin_amdgcn_exp2f(st[kt][r]);

        // pf(kt,kc) = packed st regs [8kc..8kc+7] -- permutation makes these
        // exactly keys {16kc + h2*8 + 0..7} in order.  L += 1^T·P^T; O^T += V^T·P^T
#pragma unroll
        for (int kt = 0; kt < 2; ++kt)
#pragma unroll
            for (int kc = 0; kc < 2; ++kc) {
                union { unsigned u[4]; short8 v; } pf;
#pragma unroll
                for (int i = 0; i < 4; ++i)
                    pf.u[i] = packbf(st[kt][8 * kc + 2 * i], st[kt][8 * kc + 2 * i + 1]);
                accL = __builtin_amdgcn_mfma_f32_32x32x16_bf16(ones, pf.v, accL, 0, 0, 0);
#pragma unroll
                for (int dt = 0; dt < 2; ++dt) {
                    short8 vf = *(const short8*)&Vsh[(dt * 32 + ln31) * 72 + kt * 32 + kc * 16 + h2 * 8];
                    accO[dt] = __builtin_amdgcn_mfma_f32_32x32x16_bf16(vf, pf.v, accO[dt], 0, 0, 0);
                }
            }

        // stage next tile into the other buffer (safe: everyone left it at
        // the barrier above; readers of it re-sync at next iter's barrier)
        unsigned short* wbuf = smem + ((it + 1) & 1) * 9216;
        *(short8*)&wbuf[wkoff] = ka; *(short8*)&wbuf[wkoff + 8] = kb;
        *(short8*)&wbuf[wvoff] = va; *(short8*)&wbuf[wvoff + 8] = vb;
    }

    // epilogue: direct from AGPR C-layout.  lane q = q0+ln31; regs 4g+j of
    // accO[dt] are d = dt*32 + 4*h2 + 8*g + j  -> contiguous float4 chunks.
    const float inv = 1.0f / accL[0];
    float* orow = out + ((size_t)(bb * SEQ + q0 + ln31) * NH + hh) * 64;
#pragma unroll
    for (int dt = 0; dt < 2; ++dt)
#pragma unroll
        for (int g = 0; g < 4; ++g) {
            float4 w;
            w.x = accO[dt][4 * g + 0] * inv;
            w.y = accO[dt][4 * g + 1] * inv;
            w.z = accO[dt][4 * g + 2] * inv;
            w.w = accO[dt][4 * g + 3] * inv;
            *(float4*)(orow + dt * 32 + 4 * h2 + 8 * g) = w;
        }
}

// ---------------------------------------------------------------------------
extern "C" void kernel_launch(void* const* d_in, const int* in_sizes, int n_in,
                              void* d_out, int out_size, void* d_ws, size_t ws_size,
                              hipStream_t stream) {
    const float* qf = (const float*)d_in[0];
    const float* kf = (const float*)d_in[1];
    const float* vf = (const float*)d_in[2];
    const float* Wq = (const float*)d_in[3];
    const float* bq = (const float*)d_in[4];
    const float* Wk = (const float*)d_in[5];
    const float* bk = (const float*)d_in[6];
    const float* Wv = (const float*)d_in[7];
    const float* bv = (const float*)d_in[8];

    char* ws = (char*)d_ws;
    unsigned short* Wt  = (unsigned short*)ws;               // 6 MB
    unsigned short* Qg  = (unsigned short*)(ws + 6291456);   // 16 MB [B,H,S,D]
    unsigned short* Kg  = Qg + 8388608;                      // 16 MB [B,H,S,D]
    unsigned short* Vt  = Kg + 8388608;                      // 16 MB [B,H,D,S]
    unsigned short* Ab  = Vt + 8388608;                      // 3 x 16 MB bf16 A
    float* out = (float*)d_out;

    wt_kernel<<<dim3(16, 16, 3), 256, 0, stream>>>(Wq, Wk, Wv, Wt);
    conv3_kernel<<<dim3(4096, 1, 3), 256, 0, stream>>>(qf, kf, vf, Ab);
    proj_kernel<<<dim3(64, 8, 3), 256, 0, stream>>>(Ab, Wt, bq, bk, bv, Qg, Kg, Vt);
    attn_kernel<<<dim3(16, 16, 4), 256, 0, stream>>>(Qg, Kg, Vt, out);
}